// Round 3
// baseline (230.149 us; speedup 1.0000x reference)
//
#include <hip/hip_runtime.h>
#include <hip/hip_bf16.h>

// Crop: out[i, j] = audio[i, j]            for j <  starts[i]
//       out[i, j] = audio[i, j + CROP_NUM] for j >= starts[i]
// B=128, L=262144, CROP_NUM=26214, OUT_LEN=235930.
// ~121 MB read + ~121 MB write => ~38us floor @6.3TB/s.
//
// R2: latency-oriented restructure.
//  - starts[] (512 B) staged to LDS: kills the dependent VMEM load chain
//    (ds_read same-address broadcast instead of per-lane global load).
//  - 4 independent float4 groups per thread (stride-spread) for MLP.
//  - Loads unified as 2x float2: source is 8B-aligned on BOTH sides of the
//    crop point (col is even; CROP is even), so no alignment special-casing;
//    only groups straddling starts[row] or a row boundary take a scalar path
//    (<=2 per row in the whole grid).
//  - Stores remain 16B-aligned float4 (flat index * 4).

constexpr int B_ = 128;
constexpr int L_ = 262144;
constexpr int CROP_ = 26214;
constexpr int OUT_LEN_ = L_ - CROP_;                     // 235930
constexpr unsigned TOTAL_ = (unsigned)B_ * OUT_LEN_;     // 30,199,040 (div by 4)
constexpr unsigned NGROUPS_ = TOTAL_ / 4u;               // 7,549,760
constexpr int GPT_ = 4;                                  // groups per thread

__global__ __launch_bounds__(256) void crop_kernel(const float* __restrict__ audio,
                                                   const int* __restrict__ starts,
                                                   float* __restrict__ out) {
    __shared__ int s_starts[B_];
    if (threadIdx.x < B_) s_starts[threadIdx.x] = starts[threadIdx.x];
    __syncthreads();

    unsigned t = blockIdx.x * 256u + threadIdx.x;
    unsigned stride = gridDim.x * 256u;

    unsigned g[GPT_], row[GPT_], col[GPT_];
    int s[GPT_];
    bool ok[GPT_];
    float2 a[GPT_], b[GPT_];

    // Phase 1: index math + LDS starts lookups (no global traffic).
#pragma unroll
    for (int k = 0; k < GPT_; ++k) {
        g[k] = t + (unsigned)k * stride;
        ok[k] = g[k] < NGROUPS_;
        unsigned base = ok[k] ? g[k] * 4u : 0u;
        row[k] = base / (unsigned)OUT_LEN_;              // magic-mul
        col[k] = base - row[k] * (unsigned)OUT_LEN_;
        s[k] = s_starts[row[k]];
    }

    // Phase 2: issue all global loads (4 independent per thread).
#pragma unroll
    for (int k = 0; k < GPT_; ++k) {
        if (!ok[k]) continue;
        unsigned c = col[k];
        bool in_row   = (c + 4u <= (unsigned)OUT_LEN_);
        bool straddle = ((int)c < s[k]) & ((int)c + 4 > s[k]);
        if (in_row & !straddle) {
            // Contiguous 16B from one side of the crop point; 8B-aligned.
            const float2* p = reinterpret_cast<const float2*>(
                audio + (size_t)row[k] * L_ + c + ((int)c >= s[k] ? CROP_ : 0));
            a[k] = p[0];
            b[k] = p[1];
        } else {
            // Rare: group straddles starts[row] or a row boundary.
            float r[4];
#pragma unroll
            for (int e = 0; e < 4; ++e) {
                unsigned f = g[k] * 4u + (unsigned)e;
                unsigned rw = f / (unsigned)OUT_LEN_;
                int cc = (int)(f - rw * (unsigned)OUT_LEN_);
                int ss = s_starts[rw];
                r[e] = audio[(size_t)rw * L_ + cc + (cc >= ss ? CROP_ : 0)];
            }
            a[k] = make_float2(r[0], r[1]);
            b[k] = make_float2(r[2], r[3]);
        }
    }

    // Phase 3: stores (16B-aligned).
#pragma unroll
    for (int k = 0; k < GPT_; ++k) {
        if (!ok[k]) continue;
        *reinterpret_cast<float4*>(out + (size_t)g[k] * 4u) =
            make_float4(a[k].x, a[k].y, b[k].x, b[k].y);
    }
}

extern "C" void kernel_launch(void* const* d_in, const int* in_sizes, int n_in,
                              void* d_out, int out_size, void* d_ws, size_t ws_size,
                              hipStream_t stream) {
    const float* audio = (const float*)d_in[0];
    const int* starts  = (const int*)d_in[1];
    float* out = (float*)d_out;

    int block = 256;
    unsigned threads_needed = (NGROUPS_ + GPT_ - 1) / GPT_;          // 1,887,440
    int grid = (int)((threads_needed + block - 1) / block);          // 7374
    crop_kernel<<<grid, block, 0, stream>>>(audio, starts, out);
}

// Round 5
// 213.532 us; speedup vs baseline: 1.0778x; 1.0778x over previous
//
#include <hip/hip_runtime.h>
#include <hip/hip_bf16.h>

// Crop: out[i, j] = audio[i, j]            for j <  starts[i]
//       out[i, j] = audio[i, j + CROP_NUM] for j >= starts[i]
// B=128, L=262144, CROP_NUM=26214, OUT_LEN=235930.
// Pure two-segment streaming copy: 121 MB read + 121 MB write => ~38 us floor
// @6.3 TB/s. Observed dur_us (~224) is dominated by harness reset traffic
// (512 MB ws poison ~82us + 121 MB out poison ~19us + 134 MB d2d restore
// ~42us); kernel never appears in top-5 dispatches (< 81 us).
//
// R4: non-temporal probe, fixed types. __builtin_nontemporal_* requires
// native clang vector types, not HIP_vector_type classes.

constexpr int B_ = 128;
constexpr int L_ = 262144;
constexpr int CROP_ = 26214;
constexpr int OUT_LEN_ = L_ - CROP_;                     // 235930
constexpr unsigned TOTAL_ = (unsigned)B_ * OUT_LEN_;     // 30,199,040 (div by 4)
constexpr unsigned NGROUPS_ = TOTAL_ / 4u;               // 7,549,760

typedef float v2f __attribute__((ext_vector_type(2)));
typedef float v4f __attribute__((ext_vector_type(4)));

__global__ __launch_bounds__(256) void crop_kernel(const float* __restrict__ audio,
                                                   const int* __restrict__ starts,
                                                   float* __restrict__ out) {
    unsigned t = blockIdx.x * 256u + threadIdx.x;
    unsigned base = t * 4u;
    if (base >= TOTAL_) return;

    unsigned row = base / (unsigned)OUT_LEN_;            // magic-mul
    unsigned col = base - row * (unsigned)OUT_LEN_;

    v4f v;
    if (col + 4u <= (unsigned)OUT_LEN_) {
        int s = starts[row];                             // per-row, wave-mostly-uniform
        const float* src = audio + (size_t)row * L_ + col;
        bool straddle = ((int)col < s) & ((int)col + 4 > s);
        if (!straddle) {
            // Contiguous 16B from one side of the crop point; 8B-aligned both
            // sides (col even, CROP even). Non-temporal: no reuse, skip L2.
            const v2f* p = reinterpret_cast<const v2f*>(
                src + ((int)col >= s ? CROP_ : 0));
            v2f a = __builtin_nontemporal_load(p);
            v2f b = __builtin_nontemporal_load(p + 1);
            v.x = a.x; v.y = a.y; v.z = b.x; v.w = b.y;
        } else {
            // starts[row] inside this group: <=1 group per row in whole grid.
#pragma unroll
            for (int k = 0; k < 4; ++k) {
                int c = (int)col + k;
                v[k] = src[k + (c >= s ? CROP_ : 0)];
            }
        }
    } else {
        // Group straddles a row boundary (<=127 groups total).
#pragma unroll
        for (int k = 0; k < 4; ++k) {
            unsigned f = base + k;
            unsigned rw = f / (unsigned)OUT_LEN_;
            int c = (int)(f - rw * (unsigned)OUT_LEN_);
            int s = starts[rw];
            v[k] = audio[(size_t)rw * L_ + c + (c >= s ? CROP_ : 0)];
        }
    }
    // 16B-aligned non-temporal store.
    __builtin_nontemporal_store(v, reinterpret_cast<v4f*>(out + base));
}

extern "C" void kernel_launch(void* const* d_in, const int* in_sizes, int n_in,
                              void* d_out, int out_size, void* d_ws, size_t ws_size,
                              hipStream_t stream) {
    const float* audio = (const float*)d_in[0];
    const int* starts  = (const int*)d_in[1];
    float* out = (float*)d_out;

    int block = 256;
    int grid = (int)((NGROUPS_ + (unsigned)block - 1) / (unsigned)block);  // 29492
    crop_kernel<<<grid, block, 0, stream>>>(audio, starts, out);
}